// Round 3
// baseline (460.433 us; speedup 1.0000x reference)
//
#include <hip/hip_runtime.h>

typedef __attribute__((ext_vector_type(8))) short bfrag;
typedef __attribute__((ext_vector_type(4))) float ffrag;

namespace {
constexpr int Sc = 1024, Dc = 64;
constexpr int P2 = 72;          // bf16 LDS pitch (shorts): frag b128 reads are 2-way (free)
constexpr float SCALE = 0.125f; // 1/sqrt(64)
}

__device__ __forceinline__ unsigned short f2bf(float f) {
    unsigned u = __builtin_bit_cast(unsigned, f);
    u += 0x7fffu + ((u >> 16) & 1u);
    return (unsigned short)(u >> 16);
}
__device__ __forceinline__ bfrag pack8(float4 a, float4 b) {
    bfrag r;
    r[0] = (short)f2bf(a.x); r[1] = (short)f2bf(a.y);
    r[2] = (short)f2bf(a.z); r[3] = (short)f2bf(a.w);
    r[4] = (short)f2bf(b.x); r[5] = (short)f2bf(b.y);
    r[6] = (short)f2bf(b.z); r[7] = (short)f2bf(b.w);
    return r;
}
// Load 8 contiguous f32 from a row and pack to a bf16 MFMA fragment.
__device__ __forceinline__ bfrag load_row8(const float* p) {
    float4 a = *(const float4*)(p);
    float4 b = *(const float4*)(p + 4);
    return pack8(a, b);
}
#define MFMA(a, b, c) __builtin_amdgcn_mfma_f32_16x16x32_bf16((a), (b), (c), 0, 0, 0)

__global__ __launch_bounds__(256, 2)
void relattn(const float* __restrict__ Qg, const float* __restrict__ Kg,
             const float* __restrict__ Vg, const float* __restrict__ pek,
             const float* __restrict__ pev, float* __restrict__ outg,
             float* __restrict__ pbuf)
{
    // LDS: PtA 2x9216 | VtA 2x9216 | Ts 8448 | Ws 8192 | W0 256 = 53760 B
    // Ot (64x68 f32 = 17408 B) aliases PtA (epilogue only).
    __shared__ __align__(16) char smem[53760];
    unsigned short* PtA = (unsigned short*)smem;            // [2][64][P2]
    unsigned short* VtA = (unsigned short*)(smem + 18432);  // [2][64][P2]
    float* Ts = (float*)(smem + 36864);   // [64][33]
    float* Ws = (float*)(smem + 45312);   // [64][32]  (col = jrel-1)
    float* W0 = (float*)(smem + 53504);   // [64]
    float* Ot = (float*)smem;             // [64][68], aliases PtA

    const int tid  = threadIdx.x;
    const int bh   = blockIdx.y;
    const int wv   = tid >> 6;
    const int lane = tid & 63;
    const int n    = lane & 15;
    const int quad = lane >> 4;

    const float* Qbh = Qg + (size_t)bh * Sc * Dc;
    const float* Kbh = Kg + (size_t)bh * Sc * Dc;
    const float* Vbh = Vg + (size_t)bh * Sc * Dc;
    float* pbh = pbuf + (size_t)bh * Sc * Sc;
    float* obh = outg + (size_t)bh * Sc * Dc;

    const int kp  = tid & 31;           // V-transpose k-pair
    const int vd0 = (tid >> 5) * 8;     // V-transpose d base

    for (int half = 0; half < 2; ++half) {
        const int qt = half ? (15 - (int)blockIdx.x) : (int)blockIdx.x;
        const int qrow = wv * 16 + quad * 4;   // C-layout row base for this lane

        __syncthreads();   // previous half's epilogue fully done with LDS

        // ---- Q A-frags direct from global (row = wv*16+n) ----
        const float* qsrc = Qbh + (size_t)(qt * 64 + wv * 16 + n) * Dc;
        bfrag qa0 = load_row8(qsrc + quad * 8);
        bfrag qa1 = load_row8(qsrc + 32 + quad * 8);

        // ---- zero Ws ----
        for (int idx = tid; idx < 64 * 32; idx += 256) Ws[idx] = 0.f;

        // ---- Ts = Q . pe_k^T via MFMA, B-frags direct from pe_k rows ----
        #pragma unroll
        for (int sub = 0; sub < 3; ++sub) {
            int j = sub * 16 + n;                  // 0..47 (pek has 65 rows)
            const float* psrc = pek + (size_t)j * Dc;
            bfrag b0 = load_row8(psrc + quad * 8);
            bfrag b1 = load_row8(psrc + 32 + quad * 8);
            ffrag c = {};
            c = MFMA(qa0, b0, c);
            c = MFMA(qa1, b1, c);
            if (j <= 32) {
                #pragma unroll
                for (int reg = 0; reg < 4; ++reg)
                    Ts[(qrow + reg) * 33 + j] = c[reg];
            }
        }
        __syncthreads();   // Ts / Ws ready

        float ts0[4];
        #pragma unroll
        for (int reg = 0; reg < 4; ++reg) ts0[reg] = Ts[(qrow + reg) * 33];

        // ---- zero-fill fully-masked p region; drains during sync-free pass 1 ----
        {
            const int zb = (qt + 1) * 64;
            if (zb < Sc) {
                const int z4 = (Sc - zb) >> 2;
                const float4 z = make_float4(0.f, 0.f, 0.f, 0.f);
                for (int r = 0; r < 64; ++r) {
                    float4* rp = (float4*)(pbh + (size_t)(qt * 64 + r) * Sc + zb);
                    for (int c4 = tid; c4 < z4; c4 += 256) rp[c4] = z;
                }
            }
        }

        // ================= pass 1: l = sum(exp(s)) — NO barriers =================
        float lsum[4] = {0.f, 0.f, 0.f, 0.f};
        for (int kt = 0; kt <= qt; ++kt) {
            const bool bnd = (kt >= qt - 1);
            #pragma unroll
            for (int sub = 0; sub < 4; ++sub) {
                const int k = kt * 64 + sub * 16 + n;
                const float* krow = Kbh + (size_t)k * Dc;
                bfrag b0 = load_row8(krow + quad * 8);
                bfrag b1 = load_row8(krow + 32 + quad * 8);
                ffrag c = {};
                c = MFMA(qa0, b0, c);
                c = MFMA(qa1, b1, c);
                if (!bnd) {
                    #pragma unroll
                    for (int reg = 0; reg < 4; ++reg)
                        lsum[reg] += __expf((c[reg] + ts0[reg]) * SCALE);
                } else {
                    #pragma unroll
                    for (int reg = 0; reg < 4; ++reg) {
                        int jrel = k - (qt * 64 + qrow + reg) + 32;
                        if (jrel <= 32) {
                            int jcl = jrel < 0 ? 0 : jrel;
                            lsum[reg] += __expf((c[reg] + Ts[(qrow + reg) * 33 + jcl]) * SCALE);
                        }
                    }
                }
            }
        }
        float rinv[4];
        #pragma unroll
        for (int reg = 0; reg < 4; ++reg) {
            float l = lsum[reg];
            l += __shfl_xor(l, 1);
            l += __shfl_xor(l, 2);
            l += __shfl_xor(l, 4);
            l += __shfl_xor(l, 8);
            rinv[reg] = 1.f / l;
        }

        // ============ pass 2: p + O^T = V^T P^T — ONE barrier per kt ============
        ffrag oacc[4];
        #pragma unroll
        for (int i = 0; i < 4; ++i) { ffrag z = {}; oacc[i] = z; }

        int bsel = 0;
        for (int kt = 0; kt <= qt; ++kt) {
            const bool bnd = (kt >= qt - 1);
            unsigned short* Ptb = PtA + bsel * 4608;   // 9216 B / 2
            unsigned short* Vtb = VtA + bsel * 4608;

            // V prefetch (global, no LDS yet)
            const float* vsrc = Vbh + (size_t)(kt * 64 + 2 * kp) * Dc + vd0;
            float4 v0a = *(const float4*)(vsrc);
            float4 v0b = *(const float4*)(vsrc + 4);
            float4 v1a = *(const float4*)(vsrc + Dc);
            float4 v1b = *(const float4*)(vsrc + Dc + 4);

            // QK direct from global -> p (global store + Pt bf16), Ws capture
            #pragma unroll
            for (int sub = 0; sub < 4; ++sub) {
                const int k = kt * 64 + sub * 16 + n;
                const float* krow = Kbh + (size_t)k * Dc;
                bfrag b0 = load_row8(krow + quad * 8);
                bfrag b1 = load_row8(krow + 32 + quad * 8);
                ffrag c = {};
                c = MFMA(qa0, b0, c);
                c = MFMA(qa1, b1, c);
                float* prow = pbh + (size_t)(qt * 64 + qrow) * Sc + k;
                if (!bnd) {
                    #pragma unroll
                    for (int reg = 0; reg < 4; ++reg) {
                        float p = __expf((c[reg] + ts0[reg]) * SCALE) * rinv[reg];
                        prow[(size_t)reg * Sc] = p;
                        Ptb[(qrow + reg) * P2 + sub * 16 + n] = (unsigned short)f2bf(p);
                    }
                } else {
                    #pragma unroll
                    for (int reg = 0; reg < 4; ++reg) {
                        int jrel = k - (qt * 64 + qrow + reg) + 32;
                        float p = 0.f;
                        if (jrel <= 32) {
                            int jcl = jrel < 0 ? 0 : jrel;
                            p = __expf((c[reg] + Ts[(qrow + reg) * 33 + jcl]) * SCALE) * rinv[reg];
                        }
                        prow[(size_t)reg * Sc] = p;
                        Ptb[(qrow + reg) * P2 + sub * 16 + n] = (unsigned short)f2bf(p);
                        if ((unsigned)(jrel - 1) < 32u) Ws[(qrow + reg) * 32 + jrel - 1] = p;
                    }
                }
            }
            // V transpose into Vt[d][k] (bf16 pairs)
            {
                float r0[8] = {v0a.x, v0a.y, v0a.z, v0a.w, v0b.x, v0b.y, v0b.z, v0b.w};
                float r1[8] = {v1a.x, v1a.y, v1a.z, v1a.w, v1b.x, v1b.y, v1b.z, v1b.w};
                #pragma unroll
                for (int i = 0; i < 8; ++i) {
                    unsigned pk = (unsigned)f2bf(r0[i]) | ((unsigned)f2bf(r1[i]) << 16);
                    *(unsigned*)&Vtb[(vd0 + i) * P2 + 2 * kp] = pk;
                }
            }
            __syncthreads();   // Ptb/Vtb ready; prev buffer's PV reads done (prev barrier)

            // PV: O^T += V^T . P^T
            bfrag pb0 = *(bfrag*)&Ptb[(wv * 16 + n) * P2 + quad * 8];
            bfrag pb1 = *(bfrag*)&Ptb[(wv * 16 + n) * P2 + 32 + quad * 8];
            #pragma unroll
            for (int ds = 0; ds < 4; ++ds) {
                bfrag va0 = *(bfrag*)&Vtb[(ds * 16 + n) * P2 + quad * 8];
                bfrag va1 = *(bfrag*)&Vtb[(ds * 16 + n) * P2 + 32 + quad * 8];
                oacc[ds] = MFMA(va0, pb0, oacc[ds]);
                oacc[ds] = MFMA(va1, pb1, oacc[ds]);
            }
            bsel ^= 1;
        }

        // ================= epilogue: rel-v term + store O =================
        __syncthreads();   // Ws complete; all PV frag reads done
        if (tid < 64) {
            float s = 0.f;
            #pragma unroll
            for (int j = 0; j < 32; ++j) s += Ws[tid * 32 + j];
            W0[tid] = 1.f - s;   // mass of far past (jrel<=0)
        }
        {   // PtA[0][q][jj] <- Ws (bf16), jj = jrel-1 in 0..31
            int q = tid >> 2, j0 = (tid & 3) * 8;
            #pragma unroll
            for (int i = 0; i < 8; i += 2) {
                unsigned pk = (unsigned)f2bf(Ws[q * 32 + j0 + i]) |
                              ((unsigned)f2bf(Ws[q * 32 + j0 + i + 1]) << 16);
                *(unsigned*)&PtA[q * P2 + j0 + i] = pk;
            }
        }
        {   // VtA[0][d][jj] <- pe_v[jj+1][d]
            int jj = tid >> 3, d0 = (tid & 7) * 8;
            const float* src = pev + (size_t)(jj + 1) * Dc + d0;
            float4 a = *(const float4*)(src);
            float4 b = *(const float4*)(src + 4);
            float vr[8] = {a.x, a.y, a.z, a.w, b.x, b.y, b.z, b.w};
            #pragma unroll
            for (int i = 0; i < 8; ++i)
                VtA[(d0 + i) * P2 + jj] = (unsigned short)f2bf(vr[i]);
        }
        __syncthreads();
        {
            bfrag pb = *(bfrag*)&PtA[(wv * 16 + n) * P2 + quad * 8];
            #pragma unroll
            for (int ds = 0; ds < 4; ++ds) {
                bfrag va = *(bfrag*)&VtA[(ds * 16 + n) * P2 + quad * 8];
                oacc[ds] = MFMA(va, pb, oacc[ds]);
            }
        }
        float w0q = W0[wv * 16 + n];
        __syncthreads();   // all LDS reads done before Ot overwrites PtA
        #pragma unroll
        for (int ds = 0; ds < 4; ++ds) {
            float4 ov;
            ov.x = oacc[ds][0] + w0q * pev[ds * 16 + quad * 4 + 0];
            ov.y = oacc[ds][1] + w0q * pev[ds * 16 + quad * 4 + 1];
            ov.z = oacc[ds][2] + w0q * pev[ds * 16 + quad * 4 + 2];
            ov.w = oacc[ds][3] + w0q * pev[ds * 16 + quad * 4 + 3];
            *(float4*)&Ot[(wv * 16 + n) * 68 + ds * 16 + quad * 4] = ov;
        }
        __syncthreads();
        {
            int r = tid >> 2, c0 = (tid & 3) * 16;
            float* dst = obh + (size_t)(qt * 64 + r) * Dc + c0;
            *(float4*)(dst)      = *(float4*)&Ot[r * 68 + c0];
            *(float4*)(dst + 4)  = *(float4*)&Ot[r * 68 + c0 + 4];
            *(float4*)(dst + 8)  = *(float4*)&Ot[r * 68 + c0 + 8];
            *(float4*)(dst + 12) = *(float4*)&Ot[r * 68 + c0 + 12];
        }
    }
}

extern "C" void kernel_launch(void* const* d_in, const int* in_sizes, int n_in,
                              void* d_out, int out_size, void* d_ws, size_t ws_size,
                              hipStream_t stream)
{
    const float* Q   = (const float*)d_in[0];
    const float* K   = (const float*)d_in[1];
    const float* V   = (const float*)d_in[2];
    const float* pek = (const float*)d_in[3];
    const float* pev = (const float*)d_in[4];
    float* out  = (float*)d_out;
    float* pbuf = out + (size_t)64 * Sc * Dc;   // p_attn follows output

    dim3 grid(8, 64);   // paired q-tiles (b, 15-b): uniform work per block
    relattn<<<grid, 256, 0, stream>>>(Q, K, V, pek, pev, out, pbuf);
}